// Round 2
// baseline (311.586 us; speedup 1.0000x reference)
//
#include <hip/hip_runtime.h>

using US  = unsigned short;
using bf8 = __attribute__((ext_vector_type(8))) __bf16;
using us8 = __attribute__((ext_vector_type(8))) US;
using f4  = __attribute__((ext_vector_type(4))) float;
using f8  = __attribute__((ext_vector_type(8))) float;

__device__ __forceinline__ US f2bf(float x) {
  union { float f; unsigned u; } v; v.f = x;
  unsigned r = v.u + 0x7fffu + ((v.u >> 16) & 1u);
  return (US)(r >> 16);
}

// ---------- fp32 -> bf16 elementwise, 8 elems/lane ----------
__global__ void cvt_k(const float* __restrict__ in, US* __restrict__ out, int n8) {
  int i = blockIdx.x * blockDim.x + threadIdx.x;
  if (i >= n8) return;
  f8 v = ((const f8*)in)[i];
  us8 o;
#pragma unroll
  for (int j = 0; j < 8; ++j) o[j] = f2bf(v[j]);
  ((us8*)out)[i] = o;
}

// ---------- fp32 (R x C) -> bf16 (C x R) transpose ----------
__global__ void trw_k(const float* __restrict__ in, US* __restrict__ out, int R, int C) {
  __shared__ float tile[32][33];
  int bx = blockIdx.x * 32, by = blockIdx.y * 32;
  int tx = threadIdx.x & 31, ty = threadIdx.x >> 5;
  for (int i = ty; i < 32; i += 8)
    tile[i][tx] = in[(size_t)(by + i) * C + bx + tx];
  __syncthreads();
  for (int i = ty; i < 32; i += 8)
    out[(size_t)(bx + i) * R + by + tx] = f2bf(tile[tx][i]);
}

// ---------- V slice of qkv (bf16) -> Vt[b][h][d][t] ----------
__global__ void trv_k(const US* __restrict__ qkv, US* __restrict__ vt) {
  __shared__ US tile[32][33];
  int bh = blockIdx.z;
  int b = bh >> 4;
  int t0 = blockIdx.x * 32, d0 = blockIdx.y * 32;
  int tx = threadIdx.x & 31, ty = threadIdx.x >> 5;
  const US* src = qkv + (size_t)b * 2048 * 3072 + 2048 + (bh & 15) * 64;
  for (int i = ty; i < 32; i += 8)
    tile[i][tx] = src[(size_t)(t0 + i) * 3072 + d0 + tx];
  __syncthreads();
  US* dst = vt + (size_t)bh * 64 * 2048;
  for (int i = ty; i < 32; i += 8)
    dst[(size_t)(d0 + i) * 2048 + t0 + tx] = tile[tx][i];
}

// ---------- C[M,N] = A[M,K](bf16) * Bt[N,K](bf16)^T + bias(f32) ----------
// 128x128 tile, BK=64, 256 threads (4 waves, 2x2), mfma_f32_16x16x32_bf16
template <typename OT>
__global__ void gemm_bt(const US* __restrict__ A, const US* __restrict__ Bt,
                        const float* __restrict__ bias, OT* __restrict__ out,
                        int M, int N, int K) {
  __shared__ US lA[128 * 64];
  __shared__ US lB[128 * 64];
  const int t = threadIdx.x;
  const int lane = t & 63;
  const int w = t >> 6;
  const int wr = w >> 1, wc = w & 1;
  const int l15 = lane & 15, g = lane >> 4;
  const int m0 = blockIdx.x * 128, n0 = blockIdx.y * 128;

  f4 acc[4][4] = {};

  for (int k0 = 0; k0 < K; k0 += 64) {
    __syncthreads();
#pragma unroll
    for (int i = 0; i < 4; ++i) {
      int e = i * 2048 + t * 8;
      int row = e >> 6, kc = e & 63;
      int byteoff = ((row * 64 + kc) * 2) ^ ((row & 7) << 4);  // XOR bank swizzle
      us8 va = *(const us8*)(A + (size_t)(m0 + row) * K + k0 + kc);
      *(us8*)((char*)lA + byteoff) = va;
      us8 vb = *(const us8*)(Bt + (size_t)(n0 + row) * K + k0 + kc);
      *(us8*)((char*)lB + byteoff) = vb;
    }
    __syncthreads();
#pragma unroll
    for (int ks = 0; ks < 2; ++ks) {
      bf8 af[4], bfr[4];
#pragma unroll
      for (int mi = 0; mi < 4; ++mi) {
        int row = wr * 64 + mi * 16 + l15;
        int byteoff = row * 128 + (((ks * 32 + g * 8) * 2) ^ ((row & 7) << 4));
        af[mi] = *(const bf8*)((const char*)lA + byteoff);
      }
#pragma unroll
      for (int ni = 0; ni < 4; ++ni) {
        int row = wc * 64 + ni * 16 + l15;
        int byteoff = row * 128 + (((ks * 32 + g * 8) * 2) ^ ((row & 7) << 4));
        bfr[ni] = *(const bf8*)((const char*)lB + byteoff);
      }
#pragma unroll
      for (int mi = 0; mi < 4; ++mi)
#pragma unroll
        for (int ni = 0; ni < 4; ++ni)
          acc[mi][ni] = __builtin_amdgcn_mfma_f32_16x16x32_bf16(af[mi], bfr[ni], acc[mi][ni], 0, 0, 0);
    }
  }
#pragma unroll
  for (int ni = 0; ni < 4; ++ni) {
    int col = n0 + wc * 64 + ni * 16 + l15;
    float bv = bias ? bias[col] : 0.0f;
#pragma unroll
    for (int mi = 0; mi < 4; ++mi) {
      int rowb = m0 + wr * 64 + mi * 16 + g * 4;
#pragma unroll
      for (int r = 0; r < 4; ++r) {
        float val = acc[mi][ni][r] + bv;
        if constexpr (sizeof(OT) == 2)
          out[(size_t)(rowb + r) * N + col] = f2bf(val);
        else
          out[(size_t)(rowb + r) * N + col] = val;
      }
    }
  }
}

// ---------- flash attention: 1 block = (b,h, 64 q-rows); 4 waves x 16 rows ----------
__global__ void attn_k(const US* __restrict__ qkv, const US* __restrict__ vt,
                       const int* __restrict__ mask, US* __restrict__ y) {
  const int qt = blockIdx.x;   // 0..31
  const int bh = blockIdx.y;   // 0..31
  const int b = bh >> 4;
  const int t = threadIdx.x;
  const int lane = t & 63, w = t >> 6;
  const int l15 = lane & 15, g = lane >> 4;

  __shared__ US P[4][16 * 64];  // per-wave P buffer
  US* Pw = P[w];

  const US* qbase = qkv + ((size_t)(b * 2048 + qt * 64 + w * 16)) * 3072 + (bh & 15) * 64;
  bf8 qf[2];
  qf[0] = *(const bf8*)(qbase + (size_t)l15 * 3072 + g * 8);
  qf[1] = *(const bf8*)(qbase + (size_t)l15 * 3072 + 32 + g * 8);

  const US* kbase = qkv + (size_t)b * 2048 * 3072 + 1024 + (bh & 15) * 64;
  const US* vbase = vt + (size_t)bh * 64 * 2048;
  const int* mb = mask + b * 2048;

  f4 o[4] = {};
  float mrow[4], lrow[4];
#pragma unroll
  for (int r = 0; r < 4; ++r) { mrow[r] = -1e30f; lrow[r] = 0.0f; }

  for (int j0 = 0; j0 < 2048; j0 += 64) {
    f4 s[4];
#pragma unroll
    for (int ni = 0; ni < 4; ++ni) {
      const US* kr = kbase + (size_t)(j0 + ni * 16 + l15) * 3072 + g * 8;
      bf8 kf0 = *(const bf8*)(kr);
      bf8 kf1 = *(const bf8*)(kr + 32);
      f4 z = {};
      z = __builtin_amdgcn_mfma_f32_16x16x32_bf16(qf[0], kf0, z, 0, 0, 0);
      s[ni] = __builtin_amdgcn_mfma_f32_16x16x32_bf16(qf[1], kf1, z, 0, 0, 0);
    }
    // scale + key-padding mask (D-layout: this lane's col j shared by all 4 regs)
#pragma unroll
    for (int ni = 0; ni < 4; ++ni) {
      int j = j0 + ni * 16 + l15;
      bool ok = mb[j] != 0;
#pragma unroll
      for (int r = 0; r < 4; ++r)
        s[ni][r] = ok ? s[ni][r] * 0.125f : -1e30f;
    }
    // online softmax: row i = g*4+r lives in the 16 lanes sharing g
    float fac[4];
#pragma unroll
    for (int r = 0; r < 4; ++r) {
      float pm = fmaxf(fmaxf(s[0][r], s[1][r]), fmaxf(s[2][r], s[3][r]));
      pm = fmaxf(pm, __shfl_xor(pm, 1));
      pm = fmaxf(pm, __shfl_xor(pm, 2));
      pm = fmaxf(pm, __shfl_xor(pm, 4));
      pm = fmaxf(pm, __shfl_xor(pm, 8));
      float mn = fmaxf(mrow[r], pm);
      float f = __expf(mrow[r] - mn);
      mrow[r] = mn;
      float rs = 0.0f;
#pragma unroll
      for (int ni = 0; ni < 4; ++ni) {
        float p = __expf(s[ni][r] - mn);
        s[ni][r] = p;
        rs += p;
      }
      rs += __shfl_xor(rs, 1);
      rs += __shfl_xor(rs, 2);
      rs += __shfl_xor(rs, 4);
      rs += __shfl_xor(rs, 8);
      lrow[r] = lrow[r] * f + rs;
      fac[r] = f;
    }
#pragma unroll
    for (int ni = 0; ni < 4; ++ni)
#pragma unroll
      for (int r = 0; r < 4; ++r)
        o[ni][r] *= fac[r];
    // P: D-layout -> LDS (swizzled) -> A-layout fragments
#pragma unroll
    for (int ni = 0; ni < 4; ++ni)
#pragma unroll
      for (int r = 0; r < 4; ++r) {
        int i = g * 4 + r, j = ni * 16 + l15;
        int byteoff = (i * 128 + j * 2) ^ ((i & 7) << 4);
        *(US*)((char*)Pw + byteoff) = f2bf(s[ni][r]);
      }
    __syncthreads();
    bf8 pa[2];
#pragma unroll
    for (int ks = 0; ks < 2; ++ks) {
      int byteoff = l15 * 128 + (((ks * 32 + g * 8) * 2) ^ ((l15 & 7) << 4));
      pa[ks] = *(const bf8*)((const char*)Pw + byteoff);
    }
#pragma unroll
    for (int ni = 0; ni < 4; ++ni) {
      const US* vr = vbase + (size_t)(ni * 16 + l15) * 2048 + j0 + g * 8;
      bf8 v0 = *(const bf8*)(vr);
      bf8 v1 = *(const bf8*)(vr + 32);
      o[ni] = __builtin_amdgcn_mfma_f32_16x16x32_bf16(pa[0], v0, o[ni], 0, 0, 0);
      o[ni] = __builtin_amdgcn_mfma_f32_16x16x32_bf16(pa[1], v1, o[ni], 0, 0, 0);
    }
    __syncthreads();
  }
  US* yb = y + ((size_t)(b * 2048 + qt * 64 + w * 16)) * 1024 + (bh & 15) * 64;
#pragma unroll
  for (int ni = 0; ni < 4; ++ni)
#pragma unroll
    for (int r = 0; r < 4; ++r) {
      int i = g * 4 + r, d = ni * 16 + l15;
      yb[(size_t)i * 1024 + d] = f2bf(o[ni][r] / lrow[r]);
    }
}

extern "C" void kernel_launch(void* const* d_in, const int* in_sizes, int n_in,
                              void* d_out, int out_size, void* d_ws, size_t ws_size,
                              hipStream_t stream) {
  const float* x     = (const float*)d_in[0];
  const int*   mask  = (const int*)d_in[1];
  const float* Wqkv  = (const float*)d_in[2];
  const float* bqkv  = (const float*)d_in[3];
  const float* Wproj = (const float*)d_in[4];
  const float* bproj = (const float*)d_in[5];
  float* out = (float*)d_out;

  US* xb     = (US*)d_ws;                        // 4096*1024
  US* qkvb   = xb     + (size_t)4096 * 1024;     // 4096*3072
  US* WqkvT  = qkvb   + (size_t)4096 * 3072;     // 3072*1024
  US* WprojT = WqkvT  + (size_t)3072 * 1024;     // 1024*1024
  US* Vt     = WprojT + (size_t)1024 * 1024;     // 32*64*2048
  US* yb     = Vt     + (size_t)32 * 64 * 2048;  // 4096*1024

  cvt_k<<<2048, 256, 0, stream>>>(x, xb, 4096 * 1024 / 8);
  trw_k<<<dim3(96, 32), 256, 0, stream>>>(Wqkv, WqkvT, 1024, 3072);
  trw_k<<<dim3(32, 32), 256, 0, stream>>>(Wproj, WprojT, 1024, 1024);
  gemm_bt<US><<<dim3(32, 24), 256, 0, stream>>>(xb, WqkvT, bqkv, qkvb, 4096, 3072, 1024);
  trv_k<<<dim3(64, 2, 32), 256, 0, stream>>>(qkvb, Vt);
  attn_k<<<dim3(32, 32), 256, 0, stream>>>(qkvb, Vt, mask, yb);
  gemm_bt<float><<<dim3(32, 8), 256, 0, stream>>>(yb, WprojT, bproj, out, 4096, 1024, 1024);
}

// Round 3
// 306.844 us; speedup vs baseline: 1.0155x; 1.0155x over previous
//
#include <hip/hip_runtime.h>

using US  = unsigned short;
using bf8 = __attribute__((ext_vector_type(8))) __bf16;
using us8 = __attribute__((ext_vector_type(8))) US;
using f4  = __attribute__((ext_vector_type(4))) float;
using f8  = __attribute__((ext_vector_type(8))) float;

__device__ __forceinline__ US f2bf(float x) {
  union { float f; unsigned u; } v; v.f = x;
  unsigned r = v.u + 0x7fffu + ((v.u >> 16) & 1u);
  return (US)(r >> 16);
}

// ---------- fp32 -> bf16 elementwise, 8 elems/lane ----------
__global__ void cvt_k(const float* __restrict__ in, US* __restrict__ out, int n8) {
  int i = blockIdx.x * blockDim.x + threadIdx.x;
  if (i >= n8) return;
  f8 v = ((const f8*)in)[i];
  us8 o;
#pragma unroll
  for (int j = 0; j < 8; ++j) o[j] = f2bf(v[j]);
  ((us8*)out)[i] = o;
}

// ---------- fp32 (R x C) -> bf16 (C x R) transpose ----------
__global__ void trw_k(const float* __restrict__ in, US* __restrict__ out, int R, int C) {
  __shared__ float tile[32][33];
  int bx = blockIdx.x * 32, by = blockIdx.y * 32;
  int tx = threadIdx.x & 31, ty = threadIdx.x >> 5;
  for (int i = ty; i < 32; i += 8)
    tile[i][tx] = in[(size_t)(by + i) * C + bx + tx];
  __syncthreads();
  for (int i = ty; i < 32; i += 8)
    out[(size_t)(bx + i) * R + by + tx] = f2bf(tile[tx][i]);
}

// ---------- V slice of qkv (bf16) -> Vt[b][h][d][t] ----------
__global__ void trv_k(const US* __restrict__ qkv, US* __restrict__ vt) {
  __shared__ US tile[32][33];
  int bh = blockIdx.z;
  int b = bh >> 4;
  int t0 = blockIdx.x * 32, d0 = blockIdx.y * 32;
  int tx = threadIdx.x & 31, ty = threadIdx.x >> 5;
  const US* src = qkv + (size_t)b * 2048 * 3072 + 2048 + (bh & 15) * 64;
  for (int i = ty; i < 32; i += 8)
    tile[i][tx] = src[(size_t)(t0 + i) * 3072 + d0 + tx];
  __syncthreads();
  US* dst = vt + (size_t)bh * 64 * 2048;
  for (int i = ty; i < 32; i += 8)
    dst[(size_t)(d0 + i) * 2048 + t0 + tx] = tile[tx][i];
}

// ---------- C[M,N] = A[M,K](bf16) * Bt[N,K](bf16)^T + bias(f32) ----------
template <typename OT>
__global__ void gemm_bt(const US* __restrict__ A, const US* __restrict__ Bt,
                        const float* __restrict__ bias, OT* __restrict__ out,
                        int M, int N, int K) {
  __shared__ US lA[128 * 64];
  __shared__ US lB[128 * 64];
  const int t = threadIdx.x;
  const int lane = t & 63;
  const int w = t >> 6;
  const int wr = w >> 1, wc = w & 1;
  const int l15 = lane & 15, g = lane >> 4;
  const int m0 = blockIdx.x * 128, n0 = blockIdx.y * 128;

  f4 acc[4][4] = {};

  for (int k0 = 0; k0 < K; k0 += 64) {
    __syncthreads();
#pragma unroll
    for (int i = 0; i < 4; ++i) {
      int e = i * 2048 + t * 8;
      int row = e >> 6, kc = e & 63;
      int byteoff = ((row * 64 + kc) * 2) ^ ((row & 7) << 4);
      us8 va = *(const us8*)(A + (size_t)(m0 + row) * K + k0 + kc);
      *(us8*)((char*)lA + byteoff) = va;
      us8 vb = *(const us8*)(Bt + (size_t)(n0 + row) * K + k0 + kc);
      *(us8*)((char*)lB + byteoff) = vb;
    }
    __syncthreads();
#pragma unroll
    for (int ks = 0; ks < 2; ++ks) {
      bf8 af[4], bfr[4];
#pragma unroll
      for (int mi = 0; mi < 4; ++mi) {
        int row = wr * 64 + mi * 16 + l15;
        int byteoff = row * 128 + (((ks * 32 + g * 8) * 2) ^ ((row & 7) << 4));
        af[mi] = *(const bf8*)((const char*)lA + byteoff);
      }
#pragma unroll
      for (int ni = 0; ni < 4; ++ni) {
        int row = wc * 64 + ni * 16 + l15;
        int byteoff = row * 128 + (((ks * 32 + g * 8) * 2) ^ ((row & 7) << 4));
        bfr[ni] = *(const bf8*)((const char*)lB + byteoff);
      }
#pragma unroll
      for (int mi = 0; mi < 4; ++mi)
#pragma unroll
        for (int ni = 0; ni < 4; ++ni)
          acc[mi][ni] = __builtin_amdgcn_mfma_f32_16x16x32_bf16(af[mi], bfr[ni], acc[mi][ni], 0, 0, 0);
    }
  }
#pragma unroll
  for (int ni = 0; ni < 4; ++ni) {
    int col = n0 + wc * 64 + ni * 16 + l15;
    float bv = bias ? bias[col] : 0.0f;
#pragma unroll
    for (int mi = 0; mi < 4; ++mi) {
      int rowb = m0 + wr * 64 + mi * 16 + g * 4;
#pragma unroll
      for (int r = 0; r < 4; ++r) {
        float val = acc[mi][ni][r] + bv;
        if constexpr (sizeof(OT) == 2)
          out[(size_t)(rowb + r) * N + col] = f2bf(val);
        else
          out[(size_t)(rowb + r) * N + col] = val;
      }
    }
  }
}

// ---------- flash attention: 2 waves/block, 16 q-rows/wave, no barriers ----------
__global__ __launch_bounds__(128, 4) void attn_k(const US* __restrict__ qkv,
                                                 const US* __restrict__ vt,
                                                 const int* __restrict__ mask,
                                                 US* __restrict__ y) {
  // XCD-aware bijective remap: each XCD owns 4 heads -> K/V fits its 4MB L2
  int f = blockIdx.y * 64 + blockIdx.x;        // 0..2047, dispatch order
  f = ((f & 7) << 8) | (f >> 3);               // bijective (2048 = 8*256)
  const int qt = f & 63;                       // 64 q-tiles of 32 rows
  const int bh = f >> 6;                       // 0..31
  const int b = bh >> 4;
  const int lane = threadIdx.x & 63, w = threadIdx.x >> 6;
  const int l15 = lane & 15, g = lane >> 4;

  __shared__ US P[2][16 * 64];                 // per-wave P buffer
  US* Pw = P[w];

  const int qr0 = qt * 32 + w * 16;
  const US* qbase = qkv + ((size_t)(b * 2048 + qr0)) * 3072 + (bh & 15) * 64;
  bf8 qf0 = *(const bf8*)(qbase + (size_t)l15 * 3072 + g * 8);
  bf8 qf1 = *(const bf8*)(qbase + (size_t)l15 * 3072 + 32 + g * 8);

  const US* kbase = qkv + (size_t)b * 2048 * 3072 + 1024 + (bh & 15) * 64;
  const US* vbase = vt + (size_t)bh * 64 * 2048;
  const int* mb = mask + b * 2048;

  f4 o[4] = {};
  float mrow[4], lrow[4];
#pragma unroll
  for (int r = 0; r < 4; ++r) { mrow[r] = -1e30f; lrow[r] = 0.0f; }

  const float SC = 0.125f * 1.44269504089f;    // scale * log2(e): exp2-domain softmax

  for (int j0 = 0; j0 < 2048; j0 += 64) {
    // ---- issue ALL loads first: K, V, mask (V latency hides under softmax) ----
    bf8 ka[4], kb[4], va[4], vb[4];
    int mok[4];
#pragma unroll
    for (int ni = 0; ni < 4; ++ni) {
      const US* kr = kbase + (size_t)(j0 + ni * 16 + l15) * 3072 + g * 8;
      ka[ni] = *(const bf8*)(kr);
      kb[ni] = *(const bf8*)(kr + 32);
    }
#pragma unroll
    for (int ni = 0; ni < 4; ++ni) {
      const US* vr = vbase + (size_t)(ni * 16 + l15) * 2048 + j0 + g * 8;
      va[ni] = *(const bf8*)(vr);
      vb[ni] = *(const bf8*)(vr + 32);
      mok[ni] = mb[j0 + ni * 16 + l15];
    }
    // ---- QK^T ----
    f4 s[4];
    __builtin_amdgcn_s_setprio(1);
#pragma unroll
    for (int ni = 0; ni < 4; ++ni) {
      f4 z = {};
      z = __builtin_amdgcn_mfma_f32_16x16x32_bf16(qf0, ka[ni], z, 0, 0, 0);
      s[ni] = __builtin_amdgcn_mfma_f32_16x16x32_bf16(qf1, kb[ni], s[ni] = z, 0, 0, 0);
    }
    __builtin_amdgcn_s_setprio(0);
#pragma unroll
    for (int ni = 0; ni < 4; ++ni) {
      bool ok = mok[ni] != 0;
#pragma unroll
      for (int r = 0; r < 4; ++r)
        s[ni][r] = ok ? s[ni][r] * SC : -1e30f;
    }
    // ---- online softmax (row i=g*4+r lives in 16 lanes sharing g), defer-max ----
    float pm[4];
#pragma unroll
    for (int r = 0; r < 4; ++r) {
      float p = fmaxf(fmaxf(s[0][r], s[1][r]), fmaxf(s[2][r], s[3][r]));
      p = fmaxf(p, __shfl_xor(p, 1));
      p = fmaxf(p, __shfl_xor(p, 2));
      p = fmaxf(p, __shfl_xor(p, 4));
      p = fmaxf(p, __shfl_xor(p, 8));
      pm[r] = p;
    }
    float dev = fmaxf(fmaxf(pm[0] - mrow[0], pm[1] - mrow[1]),
                      fmaxf(pm[2] - mrow[2], pm[3] - mrow[3]));
    if (!__all(dev <= 11.5f)) {                // full rescale path (rare)
      float fac[4];
#pragma unroll
      for (int r = 0; r < 4; ++r) {
        float mn = fmaxf(mrow[r], pm[r]);
        fac[r] = exp2f(mrow[r] - mn);
        mrow[r] = mn;
        lrow[r] *= fac[r];
      }
#pragma unroll
      for (int ni = 0; ni < 4; ++ni)
#pragma unroll
        for (int r = 0; r < 4; ++r)
          o[ni][r] *= fac[r];
    }
    float rs[4] = {0.f, 0.f, 0.f, 0.f};
#pragma unroll
    for (int ni = 0; ni < 4; ++ni)
#pragma unroll
      for (int r = 0; r < 4; ++r) {
        float p = exp2f(s[ni][r] - mrow[r]);
        s[ni][r] = p;
        rs[r] += p;
      }
#pragma unroll
    for (int r = 0; r < 4; ++r) {
      float t = rs[r];
      t += __shfl_xor(t, 1);
      t += __shfl_xor(t, 2);
      t += __shfl_xor(t, 4);
      t += __shfl_xor(t, 8);
      lrow[r] += t;
    }
    // ---- P: D-layout -> LDS (swizzled) -> A-layout fragments (wave-local) ----
#pragma unroll
    for (int ni = 0; ni < 4; ++ni)
#pragma unroll
      for (int r = 0; r < 4; ++r) {
        int i = g * 4 + r, j = ni * 16 + l15;
        int byteoff = (i * 128 + j * 2) ^ ((i & 7) << 4);
        *(US*)((char*)Pw + byteoff) = f2bf(s[ni][r]);
      }
    bf8 pa[2];
#pragma unroll
    for (int ks = 0; ks < 2; ++ks) {
      int byteoff = l15 * 128 + (((ks * 32 + g * 8) * 2) ^ ((l15 & 7) << 4));
      pa[ks] = *(const bf8*)((const char*)Pw + byteoff);
    }
    // ---- PV (V already resident) ----
    __builtin_amdgcn_s_setprio(1);
#pragma unroll
    for (int ni = 0; ni < 4; ++ni) {
      o[ni] = __builtin_amdgcn_mfma_f32_16x16x32_bf16(pa[0], va[ni], o[ni], 0, 0, 0);
      o[ni] = __builtin_amdgcn_mfma_f32_16x16x32_bf16(pa[1], vb[ni], o[ni], 0, 0, 0);
    }
    __builtin_amdgcn_s_setprio(0);
  }
  US* yb = y + ((size_t)(b * 2048 + qr0)) * 1024 + (bh & 15) * 64;
#pragma unroll
  for (int r = 0; r < 4; ++r) {
    float inv = 1.0f / lrow[r];
#pragma unroll
    for (int ni = 0; ni < 4; ++ni) {
      int i = g * 4 + r, d = ni * 16 + l15;
      yb[(size_t)i * 1024 + d] = f2bf(o[ni][r] * inv);
    }
  }
}

extern "C" void kernel_launch(void* const* d_in, const int* in_sizes, int n_in,
                              void* d_out, int out_size, void* d_ws, size_t ws_size,
                              hipStream_t stream) {
  const float* x     = (const float*)d_in[0];
  const int*   mask  = (const int*)d_in[1];
  const float* Wqkv  = (const float*)d_in[2];
  const float* bqkv  = (const float*)d_in[3];
  const float* Wproj = (const float*)d_in[4];
  const float* bproj = (const float*)d_in[5];
  float* out = (float*)d_out;

  US* xb     = (US*)d_ws;                        // 4096*1024
  US* qkvb   = xb     + (size_t)4096 * 1024;     // 4096*3072
  US* WqkvT  = qkvb   + (size_t)4096 * 3072;     // 3072*1024
  US* WprojT = WqkvT  + (size_t)3072 * 1024;     // 1024*1024
  US* Vt     = WprojT + (size_t)1024 * 1024;     // 32*64*2048
  US* yb     = Vt     + (size_t)32 * 64 * 2048;  // 4096*1024

  cvt_k<<<2048, 256, 0, stream>>>(x, xb, 4096 * 1024 / 8);
  trw_k<<<dim3(96, 32), 256, 0, stream>>>(Wqkv, WqkvT, 1024, 3072);
  trw_k<<<dim3(32, 32), 256, 0, stream>>>(Wproj, WprojT, 1024, 1024);
  gemm_bt<US><<<dim3(32, 24), 256, 0, stream>>>(xb, WqkvT, bqkv, qkvb, 4096, 3072, 1024);
  trv_k<<<dim3(64, 2, 32), 256, 0, stream>>>(qkvb, Vt);
  attn_k<<<dim3(64, 32), 128, 0, stream>>>(qkvb, Vt, mask, yb);
  gemm_bt<float><<<dim3(32, 8), 256, 0, stream>>>(yb, WprojT, bproj, out, 4096, 1024, 1024);
}

// Round 4
// 195.160 us; speedup vs baseline: 1.5966x; 1.5723x over previous
//
#include <hip/hip_runtime.h>

using US   = unsigned short;
using bf8  = __attribute__((ext_vector_type(8))) __bf16;
using us8  = __attribute__((ext_vector_type(8))) US;
using us4  = __attribute__((ext_vector_type(4))) US;
using f4   = __attribute__((ext_vector_type(4))) float;
using f8   = __attribute__((ext_vector_type(8))) float;
using f16v = __attribute__((ext_vector_type(16))) float;

__device__ __forceinline__ US f2bf(float x) {
  union { float f; unsigned u; } v; v.f = x;
  unsigned r = v.u + 0x7fffu + ((v.u >> 16) & 1u);
  return (US)(r >> 16);
}
__device__ __forceinline__ unsigned cvtpk(float a, float b) {
  unsigned r;
  asm("v_cvt_pk_bf16_f32 %0, %1, %2" : "=v"(r) : "v"(a), "v"(b));
  return r;
}

// ---------- fp32 -> bf16 elementwise, 8 elems/lane ----------
__global__ void cvt_k(const float* __restrict__ in, US* __restrict__ out, int n8) {
  int i = blockIdx.x * blockDim.x + threadIdx.x;
  if (i >= n8) return;
  f8 v = ((const f8*)in)[i];
  us8 o;
#pragma unroll
  for (int j = 0; j < 8; ++j) o[j] = f2bf(v[j]);
  ((us8*)out)[i] = o;
}

// ---------- fp32 (R x C) -> bf16 (C x R) transpose ----------
__global__ void trw_k(const float* __restrict__ in, US* __restrict__ out, int R, int C) {
  __shared__ float tile[32][33];
  int bx = blockIdx.x * 32, by = blockIdx.y * 32;
  int tx = threadIdx.x & 31, ty = threadIdx.x >> 5;
  for (int i = ty; i < 32; i += 8)
    tile[i][tx] = in[(size_t)(by + i) * C + bx + tx];
  __syncthreads();
  for (int i = ty; i < 32; i += 8)
    out[(size_t)(bx + i) * R + by + tx] = f2bf(tile[tx][i]);
}

// ---------- V slice of qkv (bf16) -> Vt[b][h][d][t] ----------
__global__ void trv_k(const US* __restrict__ qkv, US* __restrict__ vt) {
  __shared__ US tile[32][33];
  int bh = blockIdx.z;
  int b = bh >> 4;
  int t0 = blockIdx.x * 32, d0 = blockIdx.y * 32;
  int tx = threadIdx.x & 31, ty = threadIdx.x >> 5;
  const US* src = qkv + (size_t)b * 2048 * 3072 + 2048 + (bh & 15) * 64;
  for (int i = ty; i < 32; i += 8)
    tile[i][tx] = src[(size_t)(t0 + i) * 3072 + d0 + tx];
  __syncthreads();
  US* dst = vt + (size_t)bh * 64 * 2048;
  for (int i = ty; i < 32; i += 8)
    dst[(size_t)(d0 + i) * 2048 + t0 + tx] = tile[tx][i];
}

// ---------- C[M,N] = A[M,K](bf16) * Bt[N,K](bf16)^T + bias(f32) ----------
template <typename OT>
__global__ void gemm_bt(const US* __restrict__ A, const US* __restrict__ Bt,
                        const float* __restrict__ bias, OT* __restrict__ out,
                        int M, int N, int K) {
  __shared__ US lA[128 * 64];
  __shared__ US lB[128 * 64];
  const int t = threadIdx.x;
  const int lane = t & 63;
  const int w = t >> 6;
  const int wr = w >> 1, wc = w & 1;
  const int l15 = lane & 15, g = lane >> 4;
  const int m0 = blockIdx.x * 128, n0 = blockIdx.y * 128;

  f4 acc[4][4] = {};

  for (int k0 = 0; k0 < K; k0 += 64) {
    __syncthreads();
#pragma unroll
    for (int i = 0; i < 4; ++i) {
      int e = i * 2048 + t * 8;
      int row = e >> 6, kc = e & 63;
      int byteoff = ((row * 64 + kc) * 2) ^ ((row & 7) << 4);
      us8 va = *(const us8*)(A + (size_t)(m0 + row) * K + k0 + kc);
      *(us8*)((char*)lA + byteoff) = va;
      us8 vb = *(const us8*)(Bt + (size_t)(n0 + row) * K + k0 + kc);
      *(us8*)((char*)lB + byteoff) = vb;
    }
    __syncthreads();
#pragma unroll
    for (int ks = 0; ks < 2; ++ks) {
      bf8 af[4], bfr[4];
#pragma unroll
      for (int mi = 0; mi < 4; ++mi) {
        int row = wr * 64 + mi * 16 + l15;
        int byteoff = row * 128 + (((ks * 32 + g * 8) * 2) ^ ((row & 7) << 4));
        af[mi] = *(const bf8*)((const char*)lA + byteoff);
      }
#pragma unroll
      for (int ni = 0; ni < 4; ++ni) {
        int row = wc * 64 + ni * 16 + l15;
        int byteoff = row * 128 + (((ks * 32 + g * 8) * 2) ^ ((row & 7) << 4));
        bfr[ni] = *(const bf8*)((const char*)lB + byteoff);
      }
#pragma unroll
      for (int mi = 0; mi < 4; ++mi)
#pragma unroll
        for (int ni = 0; ni < 4; ++ni)
          acc[mi][ni] = __builtin_amdgcn_mfma_f32_16x16x32_bf16(af[mi], bfr[ni], acc[mi][ni], 0, 0, 0);
    }
  }
#pragma unroll
  for (int ni = 0; ni < 4; ++ni) {
    int col = n0 + wc * 64 + ni * 16 + l15;
    float bv = bias ? bias[col] : 0.0f;
#pragma unroll
    for (int mi = 0; mi < 4; ++mi) {
      int rowb = m0 + wr * 64 + mi * 16 + g * 4;
#pragma unroll
      for (int r = 0; r < 4; ++r) {
        float val = acc[mi][ni][r] + bv;
        if constexpr (sizeof(OT) == 2)
          out[(size_t)(rowb + r) * N + col] = f2bf(val);
        else
          out[(size_t)(rowb + r) * N + col] = val;
      }
    }
  }
}

// ---------- flash attention, swapped-operand 32x32 MFMA, lane-local softmax ----------
// Wave owns 32 q-rows; lane owns q = lane&31 (lane^32 is its partner holding the
// other half of each 64-key S column). All softmax state is lane-local scalars.
__global__ __launch_bounds__(128, 2) void attn_k(const US* __restrict__ qkv,
                                                 const US* __restrict__ vt,
                                                 const int* __restrict__ mask,
                                                 US* __restrict__ y) {
  int f = blockIdx.x;                 // 0..1023
  f = ((f & 7) << 7) | (f >> 3);      // XCD bijective remap (1024 = 8*128): 4 heads/XCD
  const int qt = f & 31;              // 32 block-tiles of 64 q-rows (2 waves x 32)
  const int bh = f >> 5;              // 0..31
  const int b = bh >> 4;
  const int lane = threadIdx.x & 63, w = threadIdx.x >> 6;
  const int l31 = lane & 31, hi = lane >> 5;
  const int qr0 = qt * 64 + w * 32;

  // Q fragments (B-layout: col=q=l31, dh = ks*16 + hi*8 + i), resident
  const US* qrow = qkv + (size_t)(b * 2048 + qr0 + l31) * 3072 + (bh & 15) * 64 + hi * 8;
  bf8 qf[4];
#pragma unroll
  for (int ks = 0; ks < 4; ++ks) qf[ks] = *(const bf8*)(qrow + ks * 16);

  const US* kbase = qkv + (size_t)b * 2048 * 3072 + 1024 + (bh & 15) * 64 + hi * 8;
  const US* vbase = vt + (size_t)bh * 64 * 2048 + (size_t)l31 * 2048 + hi * 8;
  const int* mb = mask + b * 2048;

  f16v o0 = {}, o1 = {};              // O^T: col=q=l31, rows d = r(reg,hi) (+32)
  float m = -1e30f, lrow = 0.0f;
  const float SC = 0.125f * 1.44269504089f;  // scale * log2(e)

  for (int j0 = 0; j0 < 2048; j0 += 64) {
    unsigned long long mbits = __ballot(mb[j0 + lane] != 0);
    // K fragments (A-layout: row=k=l31(+32t), dh = ks*16 + hi*8 + i)
    bf8 ka0[4], ka1[4];
#pragma unroll
    for (int ks = 0; ks < 4; ++ks) {
      ka0[ks] = *(const bf8*)(kbase + (size_t)(j0 + l31) * 3072 + ks * 16);
      ka1[ks] = *(const bf8*)(kbase + (size_t)(j0 + 32 + l31) * 3072 + ks * 16);
    }
    // S^T = K * Q : col=q, row=k
    f16v s0 = {}, s1 = {};
    __builtin_amdgcn_s_setprio(1);
#pragma unroll
    for (int ks = 0; ks < 4; ++ks) {
      s0 = __builtin_amdgcn_mfma_f32_32x32x16_bf16(ka0[ks], qf[ks], s0, 0, 0, 0);
      s1 = __builtin_amdgcn_mfma_f32_32x32x16_bf16(ka1[ks], qf[ks], s1, 0, 0, 0);
    }
    __builtin_amdgcn_s_setprio(0);
    // V fragments issued now; latency hides under softmax
    bf8 vf0[4], vf1[4];
#pragma unroll
    for (int ks = 0; ks < 4; ++ks) {
      vf0[ks] = *(const bf8*)(vbase + j0 + ks * 16);
      vf1[ks] = *(const bf8*)(vbase + 32 * 2048 + j0 + ks * 16);
    }
    // ---- lane-local online softmax over this lane's 32 keys + partner's 32 ----
    float a[16];
#pragma unroll
    for (int i = 0; i < 16; ++i) a[i] = fmaxf(s0[i], s1[i]);
#pragma unroll
    for (int st = 8; st >= 1; st >>= 1)
#pragma unroll
      for (int i = 0; i < 16; ++i)
        if (i < st) a[i] = fmaxf(a[i], a[i + st]);
    float mraw = fmaxf(a[0], __shfl_xor(a[0], 32));
    float pm = mraw * SC;
    if (!__all(pm - m <= 11.5f)) {    // rare rescale (always on first tile)
      float mn = fmaxf(m, pm);
      float fac = exp2f(m - mn);
      m = mn;
      lrow *= fac;
      o0 *= fac;
      o1 *= fac;
    }
#pragma unroll
    for (int i = 0; i < 16; ++i) {
      s0[i] = exp2f(s0[i] * SC - m);
      s1[i] = exp2f(s1[i] * SC - m);
    }
    if (~mbits != 0ULL) {             // partial mask: zero out masked keys
#pragma unroll
      for (int i = 0; i < 16; ++i) {
        int r = (i & 3) + 8 * (i >> 2) + 4 * hi;
        if (!((mbits >> r) & 1)) s0[i] = 0.0f;
        if (!((mbits >> (32 + r)) & 1)) s1[i] = 0.0f;
      }
    }
#pragma unroll
    for (int i = 0; i < 16; ++i) a[i] = s0[i] + s1[i];
#pragma unroll
    for (int st = 8; st >= 1; st >>= 1)
#pragma unroll
      for (int i = 0; i < 16; ++i)
        if (i < st) a[i] += a[i + st];
    lrow += a[0] + __shfl_xor(a[0], 32);
    // ---- P -> bf16 B-fragments (col=q, k = ks*16 + hi*8 + i) via pack+swap ----
    bf8 pf[4];
#pragma unroll
    for (int ks = 0; ks < 4; ++ks) {
      const f16v& st = (ks < 2) ? s0 : s1;
      const int R = (ks & 1) * 8;
      unsigned w0 = cvtpk(st[R + 0], st[R + 1]);
      unsigned w1 = cvtpk(st[R + 2], st[R + 3]);
      unsigned w2 = cvtpk(st[R + 4], st[R + 5]);
      unsigned w3 = cvtpk(st[R + 6], st[R + 7]);
      unsigned sa = hi ? w0 : w2;
      unsigned sb = hi ? w1 : w3;
      unsigned ra = (unsigned)__shfl_xor((int)sa, 32);
      unsigned rb = (unsigned)__shfl_xor((int)sb, 32);
      union { unsigned u[4]; bf8 v; } bld;
      bld.u[0] = hi ? ra : w0;
      bld.u[1] = hi ? rb : w1;
      bld.u[2] = hi ? w2 : ra;
      bld.u[3] = hi ? w3 : rb;
      pf[ks] = bld.v;
    }
    // ---- O^T += Vt * P ----
    __builtin_amdgcn_s_setprio(1);
#pragma unroll
    for (int ks = 0; ks < 4; ++ks) {
      o0 = __builtin_amdgcn_mfma_f32_32x32x16_bf16(vf0[ks], pf[ks], o0, 0, 0, 0);
      o1 = __builtin_amdgcn_mfma_f32_32x32x16_bf16(vf1[ks], pf[ks], o1, 0, 0, 0);
    }
    __builtin_amdgcn_s_setprio(0);
  }
  // ---- epilogue: lane-local normalize, 8B packed stores ----
  float inv = 1.0f / lrow;
  US* yrow = y + (size_t)(b * 2048 + qr0 + l31) * 1024 + (bh & 15) * 64;
#pragma unroll
  for (int qd = 0; qd < 4; ++qd) {
    us4 pk0, pk1;
#pragma unroll
    for (int j = 0; j < 4; ++j) {
      pk0[j] = f2bf(o0[qd * 4 + j] * inv);
      pk1[j] = f2bf(o1[qd * 4 + j] * inv);
    }
    *(us4*)(yrow + qd * 8 + hi * 4) = pk0;
    *(us4*)(yrow + 32 + qd * 8 + hi * 4) = pk1;
  }
}

extern "C" void kernel_launch(void* const* d_in, const int* in_sizes, int n_in,
                              void* d_out, int out_size, void* d_ws, size_t ws_size,
                              hipStream_t stream) {
  const float* x     = (const float*)d_in[0];
  const int*   mask  = (const int*)d_in[1];
  const float* Wqkv  = (const float*)d_in[2];
  const float* bqkv  = (const float*)d_in[3];
  const float* Wproj = (const float*)d_in[4];
  const float* bproj = (const float*)d_in[5];
  float* out = (float*)d_out;

  US* xb     = (US*)d_ws;                        // 4096*1024
  US* qkvb   = xb     + (size_t)4096 * 1024;     // 4096*3072
  US* WqkvT  = qkvb   + (size_t)4096 * 3072;     // 3072*1024
  US* WprojT = WqkvT  + (size_t)3072 * 1024;     // 1024*1024
  US* Vt     = WprojT + (size_t)1024 * 1024;     // 32*64*2048
  US* yb     = Vt     + (size_t)32 * 64 * 2048;  // 4096*1024

  cvt_k<<<2048, 256, 0, stream>>>(x, xb, 4096 * 1024 / 8);
  trw_k<<<dim3(96, 32), 256, 0, stream>>>(Wqkv, WqkvT, 1024, 3072);
  trw_k<<<dim3(32, 32), 256, 0, stream>>>(Wproj, WprojT, 1024, 1024);
  gemm_bt<US><<<dim3(32, 24), 256, 0, stream>>>(xb, WqkvT, bqkv, qkvb, 4096, 3072, 1024);
  trv_k<<<dim3(64, 2, 32), 256, 0, stream>>>(qkvb, Vt);
  attn_k<<<1024, 128, 0, stream>>>(qkvb, Vt, mask, yb);
  gemm_bt<float><<<dim3(32, 8), 256, 0, stream>>>(yb, WprojT, bproj, out, 4096, 1024, 1024);
}